// Round 9
// baseline (342.469 us; speedup 1.0000x reference)
//
#include <hip/hip_runtime.h>

#define BN_EPS 1e-5f
#define TN 128        // nodes per MLP block
#define NPB 256       // nodes per bucket
#define BCAP 8192     // LDS edge cap per bucket (avg 4096)
#define BH_EPB 8192   // edges per block, histogram
#define PT_EPB 4096   // edges per block, partition

typedef __attribute__((ext_vector_type(8))) short bf16x8;
typedef __attribute__((ext_vector_type(4))) float f32x4;

static __device__ __forceinline__ unsigned short f2bf(float f) {
    unsigned u = __float_as_uint(f);
    u += 0x7fff + ((u >> 16) & 1);
    return (unsigned short)(u >> 16);
}
static __device__ __forceinline__ float bf2f(unsigned short s) {
    return __uint_as_float(((unsigned)s) << 16);
}

// ============ x -> bf16 ============
__global__ __launch_bounds__(256) void xbf_kernel(
    const float* __restrict__ x, unsigned short* __restrict__ xbf, int n4)
{
    const int i = blockIdx.x * 256 + threadIdx.x;
    if (i < n4) {
        const float4 v = reinterpret_cast<const float4*>(x)[i];
        ushort4 o;
        o.x = f2bf(v.x); o.y = f2bf(v.y); o.z = f2bf(v.z); o.w = f2bf(v.w);
        reinterpret_cast<ushort4*>(xbf)[i] = o;
    }
}

// ============ one-time: W -> W^T bf16 (per layer & matrix) ============
// block b: l=b>>1, m=b&1. wtb[(b*64 + j)*64 + k] = bf16(w[l][k*64+j])
__global__ __launch_bounds__(256) void wtbf_kernel(
    const float* __restrict__ w1, const float* __restrict__ w2,
    unsigned short* __restrict__ wtb)
{
    __shared__ float sT[64 * 65];
    const int b = blockIdx.x;
    const int t = threadIdx.x;
    const float* src = ((b & 1) ? w2 : w1) + (size_t)(b >> 1) * 4096;
#pragma unroll
    for (int rr = 0; rr < 4; ++rr) {
        const int i = (rr * 256 + t) * 4;
        const float4 v = *reinterpret_cast<const float4*>(src + i);
        const int k = i >> 6, j = i & 63;
        sT[(j + 0) * 65 + k] = v.x;
        sT[(j + 1) * 65 + k] = v.y;
        sT[(j + 2) * 65 + k] = v.z;
        sT[(j + 3) * 65 + k] = v.w;
    }
    __syncthreads();
    const int j = t >> 2;
    const int kb = (t & 3) * 16;
    unsigned short o[16];
#pragma unroll
    for (int i = 0; i < 16; ++i) o[i] = f2bf(sT[j * 65 + kb + i]);
    uint4* dp = reinterpret_cast<uint4*>(wtb + ((size_t)b * 64 + j) * 64 + kb);
    dp[0] = *reinterpret_cast<const uint4*>(&o[0]);
    dp[1] = *reinterpret_cast<const uint4*>(&o[8]);
}

// ============ bucket histogram ============
__global__ __launch_bounds__(256) void bh_kernel(
    const int* __restrict__ dst, int* __restrict__ bucketCnt, int E, int NB)
{
    __shared__ int lh[512];
    const int tid = threadIdx.x;
    for (int i = tid; i < NB; i += 256) lh[i] = 0;
    __syncthreads();
    const int base = blockIdx.x * BH_EPB;
#pragma unroll
    for (int k = 0; k < BH_EPB / 256; ++k) {
        const int e = base + k * 256 + tid;
        if (e < E) atomicAdd(&lh[dst[e] >> 8], 1);
    }
    __syncthreads();
    for (int i = tid; i < NB; i += 256) {
        const int c = lh[i];
        if (c > 0) atomicAdd(&bucketCnt[i], c);
    }
}

// ============ bucket scan ============
__global__ __launch_bounds__(512) void bscan_kernel(
    const int* __restrict__ bucketCnt, int* __restrict__ bucketStart,
    int* __restrict__ bucketCursor, int NB)
{
    __shared__ int ls[512];
    const int t = threadIdx.x;
    const int v = (t < NB) ? bucketCnt[t] : 0;
    ls[t] = v;
    __syncthreads();
    for (int off = 1; off < 512; off <<= 1) {
        const int a = ls[t];
        const int b = (t >= off) ? ls[t - off] : 0;
        __syncthreads();
        ls[t] = a + b;
        __syncthreads();
    }
    const int excl = ls[t] - v;
    if (t < NB) { bucketStart[t] = excl; bucketCursor[t] = excl; }
    if (t == 511) bucketStart[NB] = ls[511];
}

// ============ partition ============
__global__ __launch_bounds__(256) void part_kernel(
    const int* __restrict__ src, const int* __restrict__ dst,
    int* __restrict__ bucketCursor, unsigned* __restrict__ part, int E, int NB)
{
    __shared__ int lh[512];
    __shared__ int lbase[512];
    const int tid = threadIdx.x;
    const int base = blockIdx.x * PT_EPB;
    for (int i = tid; i < NB; i += 256) lh[i] = 0;
    __syncthreads();
#pragma unroll
    for (int k = 0; k < PT_EPB / 256; ++k) {
        const int e = base + k * 256 + tid;
        if (e < E) atomicAdd(&lh[dst[e] >> 8], 1);
    }
    __syncthreads();
    for (int i = tid; i < NB; i += 256) {
        const int c = lh[i];
        lbase[i] = (c > 0) ? atomicAdd(&bucketCursor[i], c) : 0;
        lh[i] = 0;
    }
    __syncthreads();
#pragma unroll
    for (int k = 0; k < PT_EPB / 256; ++k) {
        const int e = base + k * 256 + tid;
        if (e < E) {
            const int d = dst[e];
            const int b = d >> 8;
            const int off = atomicAdd(&lh[b], 1);
            part[lbase[b] + off] = ((unsigned)src[e] << 8) | (unsigned)(d & 255);
        }
    }
}

// ============ per-bucket CSR build ============
__global__ __launch_bounds__(256) void bcsr_kernel(
    const unsigned* __restrict__ part, const int* __restrict__ bucketStart,
    int* __restrict__ deg, int* __restrict__ rowstart,
    int* __restrict__ eidx, int nN)
{
    __shared__ unsigned sSrc[BCAP];
    __shared__ int ldeg[256], ls[256], lcur[256];
    const int b = blockIdx.x;
    const int tid = threadIdx.x;
    const int sStart = bucketStart[b];
    const int cnt = bucketStart[b + 1] - sStart;
    const bool ldsok = (cnt <= BCAP);

    ldeg[tid] = 0;
    __syncthreads();
    for (int i = tid; i < cnt; i += 256) {
        const unsigned v = part[sStart + i];
        if (ldsok) sSrc[i] = v;
        atomicAdd(&ldeg[v & 255u], 1);
    }
    __syncthreads();
    const int dv = ldeg[tid];
    ls[tid] = dv;
    __syncthreads();
    for (int off = 1; off < 256; off <<= 1) {
        const int a = ls[tid];
        const int c = (tid >= off) ? ls[tid - off] : 0;
        __syncthreads();
        ls[tid] = a + c;
        __syncthreads();
    }
    const int excl = ls[tid] - dv;
    lcur[tid] = excl;
    const int node = b * NPB + tid;
    if (node < nN) {
        deg[node] = dv;
        rowstart[node] = sStart + excl;
    }
    __syncthreads();
    for (int i = tid; i < cnt; i += 256) {
        const unsigned v = ldsok ? sSrc[i] : part[sStart + i];
        const int dloc = (int)(v & 255u);
        const int p = atomicAdd(&lcur[dloc], 1);
        eidx[sStart + p] = (int)(v >> 8);
    }
}

// ============ graph sizes from sorted batch ============
__global__ __launch_bounds__(256) void cnt_kernel(
    const int* __restrict__ batch, int* __restrict__ cnt, int nN)
{
    const int n = blockIdx.x * 256 + threadIdx.x;
    if (n >= nN) return;
    const int g = batch[n];
    const bool firstb = (n == 0) || (batch[n - 1] != g);
    const bool lastb  = (n == nN - 1) || (batch[n + 1] != g);
    if (lastb)  atomicAdd(&cnt[g], n + 1);
    if (firstb) atomicAdd(&cnt[g], -n);
}

// ============ aggregation: agg[n] = sc*(z[n] + sum_in z[s]) + (deg+1)*sh -> bf16 ====
// 1 node/wave; 8 lanes x ushort8 (16B) per edge; 8 edges in flight; eidx prefetch.
__global__ __launch_bounds__(256) void agg_kernel(
    const unsigned short* __restrict__ z, const float* __restrict__ scsh,
    const int* __restrict__ rowstart, const int* __restrict__ deg,
    const int* __restrict__ eidx, unsigned short* __restrict__ agg, int nN)
{
    const int node = blockIdx.x * 4 + (threadIdx.x >> 6);
    if (node >= nN) return;
    const int lane = threadIdx.x & 63;
    const int q = lane >> 3;          // edge slot 0..7
    const int fe = (lane & 7) * 8;    // feature octet
    const int rs = rowstart[node];
    const int d = deg[node];

    float a[8] = {0.f, 0.f, 0.f, 0.f, 0.f, 0.f, 0.f, 0.f};
    if (q == 0) {
        const uint4 v = *reinterpret_cast<const uint4*>(z + (size_t)node * 64 + fe);
        const unsigned short* e = reinterpret_cast<const unsigned short*>(&v);
#pragma unroll
        for (int k = 0; k < 8; ++k) a[k] = bf2f(e[k]);
    }
    if (d > 0) {
        int s = eidx[rs + min(q, d - 1)];
        for (int i = 0; i < d; i += 8) {
            const int j = i + q;
            const float w = (j < d) ? 1.f : 0.f;
            const uint4 v = *reinterpret_cast<const uint4*>(z + (size_t)s * 64 + fe);
            // prefetch next slot's source index (clamped, always valid)
            s = eidx[rs + min(i + 8 + q, d - 1)];
            const unsigned short* e = reinterpret_cast<const unsigned short*>(&v);
#pragma unroll
            for (int k = 0; k < 8; ++k) a[k] = fmaf(w, bf2f(e[k]), a[k]);
        }
    }
#pragma unroll
    for (int k = 0; k < 8; ++k) {
        a[k] += __shfl_xor(a[k], 8);
        a[k] += __shfl_xor(a[k], 16);
        a[k] += __shfl_xor(a[k], 32);
    }
    if (q == 0) {
        unsigned short ob[8];
        if (scsh) {
            const float c = (float)(d + 1);
#pragma unroll
            for (int k = 0; k < 8; ++k)
                ob[k] = f2bf(fmaf(a[k], scsh[fe + k], c * scsh[64 + fe + k]));
        } else {
#pragma unroll
            for (int k = 0; k < 8; ++k) ob[k] = f2bf(a[k]);
        }
        *reinterpret_cast<uint4*>(agg + (size_t)node * 64 + fe) =
            *reinterpret_cast<const uint4*>(&ob[0]);
    }
}

// ============ MFMA MLP: z = relu(relu(A@W1+b1)@W2+b2) -> bf16, + BN stats + pool ====
// A [128x64] bf16 in LDS (pitch 72); W^T staged from pre-transposed wtb (pitch 72).
// C/D layout (HW-verified m89): col=lane&15, row=(lane>>4)*4+reg.
__global__ __launch_bounds__(256) void mlp_kernel(
    const unsigned short* __restrict__ agg, const int* __restrict__ batch,
    const unsigned short* __restrict__ wtb, const float* __restrict__ b1,
    const float* __restrict__ b2,
    unsigned short* __restrict__ zout, float* __restrict__ bnstats,
    float* __restrict__ xpz, int layer, int nN, int storeZ)
{
    __shared__ unsigned short sA[128 * 72];
    __shared__ unsigned short sW[2][64 * 72];
    __shared__ float sB[2][64];
    __shared__ float sSum[64], sSq[64];
    __shared__ float sPool[4 * 64];
    __shared__ int sBatch[128];

    const int tid = threadIdx.x;
    const int n0 = blockIdx.x * TN;

    // --- stage A: 2 threads/row, 32 bf16 (4 x uint4) each; zero-pad OOB rows ---
    {
        const int row = tid >> 1;
        const int cg = (tid & 1) * 32;
        const int node = n0 + row;
        uint4 v0 = make_uint4(0, 0, 0, 0), v1 = v0, v2 = v0, v3 = v0;
        if (node < nN) {
            const uint4* g = reinterpret_cast<const uint4*>(agg + (size_t)node * 64 + cg);
            v0 = g[0]; v1 = g[1]; v2 = g[2]; v3 = g[3];
        }
        uint4* dp = reinterpret_cast<uint4*>(&sA[row * 72 + cg]);
        dp[0] = v0; dp[1] = v1; dp[2] = v2; dp[3] = v3;
    }
    // --- stage W^T (vector copy from wtb), biases, batch, stats ---
    {
        const int m = tid >> 7;          // matrix 0/1
        const int j = (tid & 127) >> 1;  // row
        const int cg = (tid & 1) * 32;
        const uint4* g = reinterpret_cast<const uint4*>(
            wtb + (((size_t)layer * 2 + m) * 64 + j) * 64 + cg);
        uint4* dp = reinterpret_cast<uint4*>(&sW[m][j * 72 + cg]);
        dp[0] = g[0]; dp[1] = g[1]; dp[2] = g[2]; dp[3] = g[3];
        if (tid < 64) {
            sB[0][tid] = b1[layer * 64 + tid];
            sB[1][tid] = b2[layer * 64 + tid];
            sSum[tid] = 0.f; sSq[tid] = 0.f;
        }
        if (tid < 128) sBatch[tid] = (n0 + tid < nN) ? batch[n0 + tid] : -1;
        sPool[tid] = 0.f;
    }
    __syncthreads();

    const int w  = tid >> 6;
    const int l  = tid & 63;
    const int lr = l & 15;
    const int hi = l >> 4;

    f32x4 acc[2][4];
    // ---- mm1: T = relu(A @ W1 + b1) ----
#pragma unroll
    for (int rt = 0; rt < 2; ++rt)
#pragma unroll
        for (int ct = 0; ct < 4; ++ct) {
            const float bv = sB[0][ct * 16 + lr];
            acc[rt][ct] = (f32x4){bv, bv, bv, bv};
        }
#pragma unroll
    for (int kb = 0; kb < 2; ++kb) {
        const bf16x8 af0 = *reinterpret_cast<const bf16x8*>(&sA[(w * 32 + lr) * 72 + kb * 32 + hi * 8]);
        const bf16x8 af1 = *reinterpret_cast<const bf16x8*>(&sA[(w * 32 + 16 + lr) * 72 + kb * 32 + hi * 8]);
#pragma unroll
        for (int ct = 0; ct < 4; ++ct) {
            const bf16x8 bfr = *reinterpret_cast<const bf16x8*>(&sW[0][(ct * 16 + lr) * 72 + kb * 32 + hi * 8]);
            acc[0][ct] = __builtin_amdgcn_mfma_f32_16x16x32_bf16(af0, bfr, acc[0][ct], 0, 0, 0);
            acc[1][ct] = __builtin_amdgcn_mfma_f32_16x16x32_bf16(af1, bfr, acc[1][ct], 0, 0, 0);
        }
    }
    __syncthreads();   // done reading A tile
    // write T (relu, bf16) into sA
#pragma unroll
    for (int rt = 0; rt < 2; ++rt)
#pragma unroll
        for (int ct = 0; ct < 4; ++ct)
#pragma unroll
            for (int r = 0; r < 4; ++r)
                sA[(w * 32 + rt * 16 + hi * 4 + r) * 72 + ct * 16 + lr] =
                    f2bf(fmaxf(acc[rt][ct][r], 0.f));
    __syncthreads();

    // ---- mm2: Z = relu(T @ W2 + b2) ----
#pragma unroll
    for (int rt = 0; rt < 2; ++rt)
#pragma unroll
        for (int ct = 0; ct < 4; ++ct) {
            const float bv = sB[1][ct * 16 + lr];
            acc[rt][ct] = (f32x4){bv, bv, bv, bv};
        }
#pragma unroll
    for (int kb = 0; kb < 2; ++kb) {
        const bf16x8 af0 = *reinterpret_cast<const bf16x8*>(&sA[(w * 32 + lr) * 72 + kb * 32 + hi * 8]);
        const bf16x8 af1 = *reinterpret_cast<const bf16x8*>(&sA[(w * 32 + 16 + lr) * 72 + kb * 32 + hi * 8]);
#pragma unroll
        for (int ct = 0; ct < 4; ++ct) {
            const bf16x8 bfr = *reinterpret_cast<const bf16x8*>(&sW[1][(ct * 16 + lr) * 72 + kb * 32 + hi * 8]);
            acc[0][ct] = __builtin_amdgcn_mfma_f32_16x16x32_bf16(af0, bfr, acc[0][ct], 0, 0, 0);
            acc[1][ct] = __builtin_amdgcn_mfma_f32_16x16x32_bf16(af1, bfr, acc[1][ct], 0, 0, 0);
        }
    }

    // ---- epilogue: relu, z store, BN stats (rt-folded), run-length pool ----
    const int gfirst = sBatch[0];
#pragma unroll
    for (int ct = 0; ct < 4; ++ct) {
        const int j = ct * 16 + lr;
        float s = 0.f, qsum = 0.f;
#pragma unroll
        for (int rt = 0; rt < 2; ++rt) {
            int curg = -1;
            float ps = 0.f;
#pragma unroll
            for (int r = 0; r < 4; ++r) {
                const int lrow = w * 32 + rt * 16 + hi * 4 + r;
                const int node = n0 + lrow;
                const float v = fmaxf(acc[rt][ct][r], 0.f);
                if (node < nN) {
                    if (storeZ) zout[(size_t)node * 64 + j] = f2bf(v);
                    s += v; qsum += v * v;
                    const int g = sBatch[lrow];
                    if (g != curg) {
                        if (curg >= 0) {
                            const int lg = curg - gfirst;
                            if (lg < 4) atomicAdd(&sPool[lg * 64 + j], ps);
                            else        atomicAdd(&xpz[(size_t)curg * 64 + j], ps);
                        }
                        curg = g; ps = 0.f;
                    }
                    ps += v;
                }
            }
            if (curg >= 0) {
                const int lg = curg - gfirst;
                if (lg < 4) atomicAdd(&sPool[lg * 64 + j], ps);
                else        atomicAdd(&xpz[(size_t)curg * 64 + j], ps);
            }
        }
        s += __shfl_xor(s, 16); s += __shfl_xor(s, 32);
        qsum += __shfl_xor(qsum, 16); qsum += __shfl_xor(qsum, 32);
        if (hi == 0) { atomicAdd(&sSum[j], s); atomicAdd(&sSq[j], qsum); }
    }
    __syncthreads();
    {
        const int lg = tid >> 6, d = tid & 63;
        const float v = sPool[tid];
        if (v != 0.f) atomicAdd(&xpz[(size_t)(gfirst + lg) * 64 + d], v);
    }
    if (tid < 64) {
        atomicAdd(&bnstats[tid], sSum[tid]);
        atomicAdd(&bnstats[64 + tid], sSq[tid]);
    }
}

// ============ finalize: xp = sc*xpz + cnt*sh ; emit scsh; zero xpz ============
__global__ __launch_bounds__(256) void finalize_kernel(
    float* __restrict__ xp, const float* __restrict__ bnstats,
    const float* __restrict__ gamma, const float* __restrict__ beta,
    const int* __restrict__ cnt, float* __restrict__ xpz,
    float* __restrict__ scsh, int layer, int nG, float invN)
{
    const int i = blockIdx.x * 256 + threadIdx.x;
    if (i >= nG * 64) return;
    const int g = i >> 6, d = i & 63;
    const float mean = bnstats[d] * invN;
    const float var  = fmaxf(bnstats[64 + d] * invN - mean * mean, 0.f);
    const float sc = gamma[layer * 64 + d] * rsqrtf(var + BN_EPS);
    const float sh = beta[layer * 64 + d] - mean * sc;
    if (g == 0) { scsh[d] = sc; scsh[64 + d] = sh; }
    xp[(size_t)g * 192 + layer * 64 + d] = fmaf(sc, xpz[i], (float)cnt[g] * sh);
    xpz[i] = 0.f;
}

// ============ head ============
__global__ __launch_bounds__(256) void final_kernel(
    const float* __restrict__ xp, const float* __restrict__ lin_w,
    const float* __restrict__ lin_b, const float* __restrict__ fin_w,
    const float* __restrict__ fin_b, float* __restrict__ out, int nG)
{
    const int g = (blockIdx.x * 256 + threadIdx.x) >> 6;
    const int lane = threadIdx.x & 63;
    if (g >= nG) return;
    const float* xr = xp + (size_t)g * 192;
    float acc = lin_b[lane];
    for (int k = 0; k < 192; ++k) acc = fmaf(xr[k], lin_w[k * 64 + lane], acc);
    const float t = fmaxf(acc, 0.f);
    float o[10];
#pragma unroll
    for (int c = 0; c < 10; ++c) {
        float p = t * fin_w[lane * 10 + c];
#pragma unroll
        for (int off = 32; off > 0; off >>= 1) p += __shfl_xor(p, off);
        o[c] = p + fin_b[c];
    }
    float m = o[0];
#pragma unroll
    for (int c = 1; c < 10; ++c) m = fmaxf(m, o[c]);
    float Z = 0.f;
#pragma unroll
    for (int c = 0; c < 10; ++c) Z += expf(o[c] - m);
    const float lz = m + logf(Z);
#pragma unroll
    for (int c = 0; c < 10; ++c)
        if (lane == c) out[(size_t)g * 10 + c] = o[c] - lz;
}

extern "C" void kernel_launch(void* const* d_in, const int* in_sizes, int n_in,
                              void* d_out, int out_size, void* d_ws, size_t ws_size,
                              hipStream_t stream)
{
    const float* x     = (const float*)d_in[0];
    const int*   ei    = (const int*)d_in[1];
    const int*   batch = (const int*)d_in[2];
    const float* w1    = (const float*)d_in[3];
    const float* b1    = (const float*)d_in[4];
    const float* w2    = (const float*)d_in[5];
    const float* b2    = (const float*)d_in[6];
    const float* gamma = (const float*)d_in[7];
    const float* beta  = (const float*)d_in[8];
    const float* lin_w = (const float*)d_in[9];
    const float* lin_b = (const float*)d_in[10];
    const float* fin_w = (const float*)d_in[11];
    const float* fin_b = (const float*)d_in[12];
    float* out = (float*)d_out;

    const int N = in_sizes[0] / 64;
    const int E = in_sizes[1] / 2;
    const int L = in_sizes[3] / 4096;
    const int G = out_size / 10;
    const float invN = 1.0f / (float)N;
    const int NB = (N + NPB - 1) / NPB;

    char* ws = (char*)d_ws;
    size_t off = 0;
    auto alloc = [&](size_t bytes) -> void* {
        void* p = ws + off;
        off += (bytes + 255) & ~(size_t)255;
        return p;
    };
    unsigned short* xbf = (unsigned short*)alloc((size_t)N * 64 * 2);
    unsigned short* z0  = (unsigned short*)alloc((size_t)N * 64 * 2);
    unsigned short* z1  = (unsigned short*)alloc((size_t)N * 64 * 2);
    unsigned short* aggbuf = (unsigned short*)alloc((size_t)N * 64 * 2);
    unsigned short* wtb = (unsigned short*)alloc((size_t)L * 2 * 4096 * 2);
    float* xp      = (float*)alloc((size_t)G * 192 * 4);
    float* xpz     = (float*)alloc((size_t)G * 64 * 4);
    float* bnstats = (float*)alloc((size_t)L * 128 * 4);
    float* scsh    = (float*)alloc(128 * 4);
    int*   cnt      = (int*)alloc((size_t)G * 4);
    int*   deg      = (int*)alloc((size_t)N * 4);
    int*   rowstart = (int*)alloc((size_t)N * 4);
    int*   eidx     = (int*)alloc((size_t)E * 4);
    unsigned* part  = (unsigned*)alloc((size_t)E * 4);
    int*   bucketCnt    = (int*)alloc((size_t)NB * 4);
    int*   bucketStart  = (int*)alloc((size_t)(NB + 1) * 4);
    int*   bucketCursor = (int*)alloc((size_t)NB * 4);

    const int* srcIdx = ei;
    const int* dstIdx = ei + E;

    // ---- setup: bucketed CSR + counts + x->bf16 + W^T ----
    hipMemsetAsync(bucketCnt, 0, (size_t)NB * 4, stream);
    hipMemsetAsync(bnstats, 0, (size_t)L * 128 * 4, stream);
    hipMemsetAsync(xpz, 0, (size_t)G * 64 * 4, stream);
    hipMemsetAsync(cnt, 0, (size_t)G * 4, stream);
    bh_kernel<<<(E + BH_EPB - 1) / BH_EPB, 256, 0, stream>>>(dstIdx, bucketCnt, E, NB);
    bscan_kernel<<<1, 512, 0, stream>>>(bucketCnt, bucketStart, bucketCursor, NB);
    part_kernel<<<(E + PT_EPB - 1) / PT_EPB, 256, 0, stream>>>(
        srcIdx, dstIdx, bucketCursor, part, E, NB);
    bcsr_kernel<<<NB, 256, 0, stream>>>(part, bucketStart, deg, rowstart, eidx, N);
    cnt_kernel<<<(N + 255) / 256, 256, 0, stream>>>(batch, cnt, N);
    xbf_kernel<<<(N * 16 + 255) / 256, 256, 0, stream>>>(x, xbf, N * 16);
    wtbf_kernel<<<L * 2, 256, 0, stream>>>(w1, w2, wtb);

    const int nAggBlk = (N + 3) / 4;
    const int nMlpBlk = (N + TN - 1) / TN;
    unsigned short* zprev = xbf;
    unsigned short* zcur = z0;
    for (int l = 0; l < L; ++l) {
        agg_kernel<<<nAggBlk, 256, 0, stream>>>(
            zprev, (l == 0) ? nullptr : scsh,
            rowstart, deg, eidx, aggbuf, N);
        mlp_kernel<<<nMlpBlk, 256, 0, stream>>>(
            aggbuf, batch, wtb, b1, b2,
            zcur, bnstats + (size_t)l * 128, xpz, l, N, (l < L - 1) ? 1 : 0);
        finalize_kernel<<<(G * 64 + 255) / 256, 256, 0, stream>>>(
            xp, bnstats + (size_t)l * 128, gamma, beta, cnt, xpz, scsh, l, G, invN);
        zprev = zcur;
        zcur = (zcur == z0) ? z1 : z0;
    }
    final_kernel<<<(G * 64 + 255) / 256, 256, 0, stream>>>(xp, lin_w, lin_b,
                                                           fin_w, fin_b, out, G);
}